// Round 1
// baseline (685.670 us; speedup 1.0000x reference)
//
#include <hip/hip_runtime.h>

#define NORM 0.35355339059327373f  // 64^-0.25
#define EPS 1e-6f

// ws layout: sums[512][16640] f32: [0:256)=Ksum[m], [256:16640)=Ssum[m][e]
// blk = bh*32 + chunk; per-chunk data offset = blk*128*64 = blk*8192

__global__ __launch_bounds__(256) void k1_chunksums(const float* __restrict__ k,
    const float* __restrict__ v, const float* __restrict__ proj,
    float* __restrict__ sums) {
  __shared__ float k_lds[8192];
  __shared__ float v_lds[8192];
  int blk = blockIdx.x;
  int t = threadIdx.x;           // t = feature m (0..255)
  const float4* kb = (const float4*)(k + (size_t)blk * 8192);
  const float4* vb = (const float4*)(v + (size_t)blk * 8192);
  for (int i = t; i < 2048; i += 256) {
    ((float4*)k_lds)[i] = kb[i];
    ((float4*)v_lds)[i] = vb[i];
  }
  float pr[64];
  const float* pp = proj + (size_t)t * 64;
  #pragma unroll
  for (int d = 0; d < 64; d++) pr[d] = pp[d] * NORM;
  __syncthreads();
  float ksum = 0.f;
  float acc[64];
  #pragma unroll
  for (int e = 0; e < 64; e++) acc[e] = 0.f;
  for (int j = 0; j < 128; j++) {
    float s = 0.f;
    #pragma unroll
    for (int d = 0; d < 64; d++) s += pr[d] * k_lds[j * 64 + d];
    float kp = 1.f / (1.f + __expf(-s)) + EPS;
    ksum += kp;
    #pragma unroll
    for (int e = 0; e < 64; e++) acc[e] += kp * v_lds[j * 64 + e];
  }
  float* outp = sums + (size_t)blk * 16640;
  outp[t] = ksum;
  #pragma unroll
  for (int e = 0; e < 64; e += 4) {
    *(float4*)(outp + 256 + t * 64 + e) =
        make_float4(acc[e], acc[e + 1], acc[e + 2], acc[e + 3]);
  }
}

// exclusive scan over the 32 chunks of each head, in place
__global__ __launch_bounds__(256) void k2_scan(float* __restrict__ sums) {
  int bh = blockIdx.x >> 3;
  int part = blockIdx.x & 7;
  int t = threadIdx.x;
  int e0 = part * 2080;
  int e1 = e0 + 2080;
  if (e1 > 16640) e1 = 16640;
  for (int e = e0 + t; e < e1; e += 256) {
    float run = 0.f;
    float* p = sums + (size_t)bh * (32 * 16640) + e;
    #pragma unroll 4
    for (int c = 0; c < 32; c++) {
      float tmp = p[(size_t)c * 16640];
      p[(size_t)c * 16640] = run;
      run += tmp;
    }
  }
}

__global__ __launch_bounds__(512, 1) void k3_out(const float* __restrict__ q,
    const float* __restrict__ k, const float* __restrict__ v,
    const float* __restrict__ proj, const float* __restrict__ sums,
    float* __restrict__ out) {
  __shared__ float R0[16384];  // q[128][64] | k[128][64]  -> later AT[128][128]
  __shared__ float R1[16384];  // PT[64][128] | KT[64][128] -> later V[128][64] | den[128]
  float* q_lds = R0;
  float* k_lds = R0 + 8192;
  float* PT = R1;
  float* KT = R1 + 8192;
  float* AT = R0;
  float* Vl = R1;
  float* den = R1 + 8192;

  int blk = blockIdx.x;
  int t = threadIdx.x;
  int ti = t >> 5;  // 0..15 : owns A rows 8*ti..8*ti+7
  int tj = t & 31;  // 0..31 : owns A cols tj, tj+32, tj+64, tj+96 ; out cols 2tj..2tj+1
  const float* qb = q + (size_t)blk * 8192;
  const float* kb = k + (size_t)blk * 8192;
  const float* vb = v + (size_t)blk * 8192;
  const float* carry = sums + (size_t)blk * 16640;
  float* ob = out + (size_t)blk * 8192;

  for (int i = t; i < 2048; i += 512) {
    ((float4*)q_lds)[i] = ((const float4*)qb)[i];
    ((float4*)k_lds)[i] = ((const float4*)kb)[i];
  }
  __syncthreads();

  float A[8][4];
  float O[8][2];
  float dqr[8];
  #pragma unroll
  for (int r = 0; r < 8; r++) {
    dqr[r] = 0.f; O[r][0] = 0.f; O[r][1] = 0.f;
    #pragma unroll
    for (int c = 0; c < 4; c++) A[r][c] = 0.f;
  }

  int fx = t >> 3;          // feature within tile (0..63)
  int xr = (t & 7) << 4;    // row base for feature compute (16 rows)

  for (int mt = 0; mt < 4; mt++) {
    // ---- feature phase: compute qp/kp tile (f-major) ----
    {
      float4 pr[16];
      const float4* pp = (const float4*)(proj + (size_t)(mt * 64 + fx) * 64);
      #pragma unroll
      for (int dd = 0; dd < 16; dd++) pr[dd] = pp[dd];
      #pragma unroll
      for (int il4 = 0; il4 < 4; il4++) {
        float wp[4], wk[4];
        #pragma unroll
        for (int u = 0; u < 4; u++) {
          int i = xr + il4 * 4 + u;
          const float4* qr = (const float4*)(q_lds + i * 64);
          const float4* kr = (const float4*)(k_lds + i * 64);
          float sq = 0.f, sk = 0.f;
          #pragma unroll
          for (int dd = 0; dd < 16; dd++) {
            float4 qv = qr[dd], kv = kr[dd], pv = pr[dd];
            sq += qv.x * pv.x; sq += qv.y * pv.y; sq += qv.z * pv.z; sq += qv.w * pv.w;
            sk += kv.x * pv.x; sk += kv.y * pv.y; sk += kv.z * pv.z; sk += kv.w * pv.w;
          }
          wp[u] = 1.f / (1.f + __expf(-NORM * sq)) + EPS;
          wk[u] = 1.f / (1.f + __expf(-NORM * sk)) + EPS;
        }
        *(float4*)(PT + fx * 128 + xr + il4 * 4) = make_float4(wp[0], wp[1], wp[2], wp[3]);
        *(float4*)(KT + fx * 128 + xr + il4 * 4) = make_float4(wk[0], wk[1], wk[2], wk[3]);
      }
    }
    __syncthreads();
    // ---- GEMM phase: A += Qp Kp^T ; O += Qp S_prev ; dqr += Qp (K_prev+eps) ----
    const float* Sg = carry + 256 + (size_t)(mt * 64) * 64;
    const float* Kg = carry + mt * 64;
    #pragma unroll 2
    for (int f = 0; f < 64; f++) {
      float4 p0 = *(const float4*)(PT + f * 128 + 8 * ti);
      float4 p1 = *(const float4*)(PT + f * 128 + 8 * ti + 4);
      float pv[8] = {p0.x, p0.y, p0.z, p0.w, p1.x, p1.y, p1.z, p1.w};
      float kt0 = KT[f * 128 + tj];
      float kt1 = KT[f * 128 + 32 + tj];
      float kt2 = KT[f * 128 + 64 + tj];
      float kt3 = KT[f * 128 + 96 + tj];
      float2 sv = *(const float2*)(Sg + f * 64 + 2 * tj);
      float kq = Kg[f] + EPS;
      #pragma unroll
      for (int r = 0; r < 8; r++) {
        A[r][0] += pv[r] * kt0;
        A[r][1] += pv[r] * kt1;
        A[r][2] += pv[r] * kt2;
        A[r][3] += pv[r] * kt3;
        O[r][0] += pv[r] * sv.x;
        O[r][1] += pv[r] * sv.y;
        dqr[r]  += pv[r] * kq;
      }
    }
    __syncthreads();
  }

  // ---- phase B: mask A, rowsum-reduce, write swizzled AT, stage V, write den ----
  float rs[8];
  #pragma unroll
  for (int r = 0; r < 8; r++) {
    int i = 8 * ti + r;
    float s = 0.f;
    #pragma unroll
    for (int c = 0; c < 4; c++) {
      int j = tj + 32 * c;
      float a = (j <= i) ? A[r][c] : 0.f;
      A[r][c] = a;
      s += a;
    }
    #pragma unroll
    for (int sh = 1; sh < 32; sh <<= 1) s += __shfl_xor(s, sh);
    rs[r] = s;
  }
  #pragma unroll
  for (int c = 0; c < 4; c++) {
    int j = tj + 32 * c;
    int sw = (j & 7) << 2;
    *(float4*)(AT + j * 128 + ((((2 * ti)    ) ^ sw) << 2)) =
        make_float4(A[0][c], A[1][c], A[2][c], A[3][c]);
    *(float4*)(AT + j * 128 + ((((2 * ti) + 1) ^ sw) << 2)) =
        make_float4(A[4][c], A[5][c], A[6][c], A[7][c]);
  }
  for (int i = t; i < 2048; i += 512) {
    ((float4*)Vl)[i] = ((const float4*)vb)[i];
  }
  if (tj == 0) {
    #pragma unroll
    for (int r = 0; r < 8; r++) den[8 * ti + r] = dqr[r] + rs[r];
  }
  __syncthreads();

  // ---- phase C: O += A_masked @ V ----
  #pragma unroll 2
  for (int j = 0; j < 128; j++) {
    int sw = (j & 7) << 2;
    float4 a0 = *(const float4*)(AT + j * 128 + ((((2 * ti)    ) ^ sw) << 2));
    float4 a1 = *(const float4*)(AT + j * 128 + ((((2 * ti) + 1) ^ sw) << 2));
    float2 vv = *(const float2*)(Vl + j * 64 + 2 * tj);
    float av[8] = {a0.x, a0.y, a0.z, a0.w, a1.x, a1.y, a1.z, a1.w};
    #pragma unroll
    for (int r = 0; r < 8; r++) {
      O[r][0] += av[r] * vv.x;
      O[r][1] += av[r] * vv.y;
    }
  }

  #pragma unroll
  for (int r = 0; r < 8; r++) {
    int i = 8 * ti + r;
    float dinv = 1.f / den[i];
    *(float2*)(ob + (size_t)i * 64 + 2 * tj) = make_float2(O[r][0] * dinv, O[r][1] * dinv);
  }
}

extern "C" void kernel_launch(void* const* d_in, const int* in_sizes, int n_in,
                              void* d_out, int out_size, void* d_ws, size_t ws_size,
                              hipStream_t stream) {
  const float* q = (const float*)d_in[0];
  const float* k = (const float*)d_in[1];
  const float* v = (const float*)d_in[2];
  const float* proj = (const float*)d_in[3];
  float* out = (float*)d_out;
  float* sums = (float*)d_ws;  // 512*16640*4 = ~34 MB

  k1_chunksums<<<512, 256, 0, stream>>>(k, v, proj, sums);
  k2_scan<<<128, 256, 0, stream>>>(sums);
  k3_out<<<512, 512, 0, stream>>>(q, k, v, proj, sums, out);
}

// Round 3
// 100.428 us; speedup vs baseline: 6.8275x; 6.8275x over previous
//
#include <hip/hip_runtime.h>

#define NORM 0.35355339059327373f  // 64^-0.25
#define EPS 1e-6f

typedef __attribute__((ext_vector_type(8))) short short8;
typedef __attribute__((ext_vector_type(4))) float floatx4;

static __device__ __forceinline__ ushort f2bf(float x) {
  union { float f; unsigned u; } a; a.f = x;
  unsigned r = a.u + 0x7FFFu + ((a.u >> 16) & 1u);
  return (ushort)(r >> 16);
}
static __device__ __forceinline__ float bf2f(ushort h) {
  union { unsigned u; float f; } a; a.u = ((unsigned)h) << 16; return a.f;
}
static __device__ __forceinline__ float sigm(float s) {
  return 1.f / (1.f + __expf(-s)) + EPS;
}
#define MFMA __builtin_amdgcn_mfma_f32_16x16x32_bf16

// ws layout per chunk record (blk = bh*32 + chunk), 16640 f32:
//   [0:256)      Ksum[f]
//   [256:16640)  St[e][f]  e-major, 64 x 256
// K2 turns per-chunk sums into exclusive prefixes (carry-in for each chunk).

// ---------------- K1: per-chunk sums (MFMA) ----------------
__global__ __launch_bounds__(512, 1) void k1_chunksums(
    const float* __restrict__ k, const float* __restrict__ v,
    const float* __restrict__ proj, float* __restrict__ sums) {
  __shared__ ushort xk[128 * 72];    // k chunk, pos-major bf16, pad 8
  __shared__ ushort prj[256 * 72];   // proj*NORM bf16 [feat][d]
  __shared__ ushort kpt[256 * 136];  // Kp feat-major [feat][pos]
  __shared__ ushort vt[64 * 136];    // V e-major [e][pos]
  const int t = threadIdx.x;
  const int w = t >> 6, l = t & 63, lr = l & 15, lg = l >> 4;
  const int blk = blockIdx.x;
  const float* kg = k + (size_t)blk * 8192;
  const float* vg = v + (size_t)blk * 8192;

  for (int id = t; id < 2048; id += 512) {
    float4 a = ((const float4*)kg)[id];
    int row = id >> 4, c = (id & 15) * 4;
    *(ushort4*)&xk[row * 72 + c] =
        make_ushort4(f2bf(a.x), f2bf(a.y), f2bf(a.z), f2bf(a.w));
  }
  for (int id = t; id < 4096; id += 512) {
    float4 a = ((const float4*)proj)[id];
    int row = id >> 4, c = (id & 15) * 4;
    *(ushort4*)&prj[row * 72 + c] =
        make_ushort4(f2bf(a.x * NORM), f2bf(a.y * NORM),
                     f2bf(a.z * NORM), f2bf(a.w * NORM));
  }
  for (int id = t; id < 2048; id += 512) {
    float4 a = ((const float4*)vg)[id];
    int pos = id >> 4, e = (id & 15) * 4;
    vt[(e + 0) * 136 + pos] = f2bf(a.x);
    vt[(e + 1) * 136 + pos] = f2bf(a.y);
    vt[(e + 2) * 136 + pos] = f2bf(a.z);
    vt[(e + 3) * 136 + pos] = f2bf(a.w);
  }
  __syncthreads();

  // scores-GEMM: M=pos(128), N=feat(256), K=d(64). wave w = pos-block w.
  // C: col=feat(l&15), row=pos((l>>4)*4+r) -> 4 consecutive pos: pack b64 to kpt
  floatx4 acc[16];
  #pragma unroll
  for (int fb = 0; fb < 16; ++fb) acc[fb] = (floatx4){0.f, 0.f, 0.f, 0.f};
  #pragma unroll
  for (int ks = 0; ks < 2; ++ks) {
    short8 a = *(const short8*)&xk[(w * 16 + lr) * 72 + ks * 32 + lg * 8];
    #pragma unroll
    for (int fb = 0; fb < 16; ++fb) {
      short8 b = *(const short8*)&prj[(fb * 16 + lr) * 72 + ks * 32 + lg * 8];
      acc[fb] = MFMA(a, b, acc[fb], 0, 0, 0);
    }
  }
  #pragma unroll
  for (int fb = 0; fb < 16; ++fb) {
    ushort4 u = make_ushort4(f2bf(sigm(acc[fb][0])), f2bf(sigm(acc[fb][1])),
                             f2bf(sigm(acc[fb][2])), f2bf(sigm(acc[fb][3])));
    *(ushort4*)&kpt[(fb * 16 + lr) * 136 + w * 16 + lg * 4] = u;
  }
  __syncthreads();

  float* wsb = sums + (size_t)blk * 16640;
  // Ksum: row sums of kpt
  if (t < 256) {
    float s = 0.f;
    #pragma unroll
    for (int i = 0; i < 16; ++i) {
      short8 vv = *(const short8*)&kpt[t * 136 + i * 8];
      #pragma unroll
      for (int j = 0; j < 8; ++j) s += bf2f((ushort)vv[j]);
    }
    wsb[t] = s;
  }

  // S-GEMM: S[f][e] = Kp^T V : M=feat(256), N=e(64), K=pos(128)
  // wave w: feat-blocks {2w,2w+1} x 4 e-blocks
  floatx4 sacc[2][4];
  #pragma unroll
  for (int f2 = 0; f2 < 2; ++f2)
    #pragma unroll
    for (int eb = 0; eb < 4; ++eb) sacc[f2][eb] = (floatx4){0.f, 0.f, 0.f, 0.f};
  #pragma unroll
  for (int ks = 0; ks < 4; ++ks) {
    short8 b[4];
    #pragma unroll
    for (int eb = 0; eb < 4; ++eb)
      b[eb] = *(const short8*)&vt[(eb * 16 + lr) * 136 + ks * 32 + lg * 8];
    #pragma unroll
    for (int f2 = 0; f2 < 2; ++f2) {
      short8 a = *(const short8*)&kpt[((2 * w + f2) * 16 + lr) * 136 + ks * 32 + lg * 8];
      #pragma unroll
      for (int eb = 0; eb < 4; ++eb)
        sacc[f2][eb] = MFMA(a, b[eb], sacc[f2][eb], 0, 0, 0);
    }
  }
  // C: col=e(l&15), row=feat -> 4 consecutive feats: float4 to global St[e][f]
  float* stg = wsb + 256;
  #pragma unroll
  for (int f2 = 0; f2 < 2; ++f2)
    #pragma unroll
    for (int eb = 0; eb < 4; ++eb) {
      float4 o = make_float4(sacc[f2][eb][0], sacc[f2][eb][1],
                             sacc[f2][eb][2], sacc[f2][eb][3]);
      *(float4*)(stg + (size_t)(eb * 16 + lr) * 256 + (2 * w + f2) * 16 + lg * 4) = o;
    }
}

// ---------------- K2: exclusive scan over 32 chunks per head ----------------
// one thread per record element; grid = 16 heads * 65 parts of 256
__global__ __launch_bounds__(256) void k2_scan(float* __restrict__ sums) {
  int bh = blockIdx.x / 65;
  int part = blockIdx.x % 65;
  int e = part * 256 + threadIdx.x;
  float run = 0.f;
  float* p = sums + (size_t)bh * (32 * 16640) + e;
  #pragma unroll 4
  for (int c = 0; c < 32; c++) {
    float tmp = p[(size_t)c * 16640];
    p[(size_t)c * 16640] = run;
    run += tmp;
  }
}

// ---------------- K3: per-chunk output (MFMA) ----------------
__global__ __launch_bounds__(512, 1) void k3_out(
    const float* __restrict__ q, const float* __restrict__ k,
    const float* __restrict__ v, const float* __restrict__ proj,
    const float* __restrict__ sums, float* __restrict__ out) {
  __shared__ union {
    struct { ushort xq[128 * 72]; ushort xk[128 * 72]; ushort prj[128 * 72]; } p1;
    struct { ushort ab[128 * 136]; ushort vt[64 * 136]; } p2;
  } r0;
  __shared__ ushort qp[128 * 136];   // Qp pos-major [pos][f_local], per f-half
  __shared__ ushort kp[128 * 136];   // Kp pos-major
  __shared__ ushort sth[64 * 136];   // S_prev^T e-major bf16, per f-half
  __shared__ float kprev[256];
  __shared__ float dqr[128];
  __shared__ float den[128];

  const int t = threadIdx.x;
  const int w = t >> 6, l = t & 63, lr = l & 15, lg = l >> 4;
  const int blk = blockIdx.x;
  const float* qg = q + (size_t)blk * 8192;
  const float* kg = k + (size_t)blk * 8192;
  const float* vg = v + (size_t)blk * 8192;
  const float* wsb = sums + (size_t)blk * 16640;
  float* outg = out + (size_t)blk * 8192;

  for (int id = t; id < 2048; id += 512) {
    float4 a = ((const float4*)qg)[id];
    float4 c = ((const float4*)kg)[id];
    int row = id >> 4, cc = (id & 15) * 4;
    *(ushort4*)&r0.p1.xq[row * 72 + cc] =
        make_ushort4(f2bf(a.x), f2bf(a.y), f2bf(a.z), f2bf(a.w));
    *(ushort4*)&r0.p1.xk[row * 72 + cc] =
        make_ushort4(f2bf(c.x), f2bf(c.y), f2bf(c.z), f2bf(c.w));
  }
  if (t < 256) kprev[t] = wsb[t];
  if (t < 128) dqr[t] = 0.f;

  floatx4 Aacc[8];
  floatx4 Oacc[4];
  #pragma unroll
  for (int i = 0; i < 8; ++i) Aacc[i] = (floatx4){0.f, 0.f, 0.f, 0.f};
  #pragma unroll
  for (int i = 0; i < 4; ++i) Oacc[i] = (floatx4){0.f, 0.f, 0.f, 0.f};

  for (int fh = 0; fh < 2; ++fh) {
    // stage proj half (feats fh*128..+127) and St half
    for (int id = t; id < 2048; id += 512) {
      float4 a = ((const float4*)(proj + (size_t)fh * 8192))[id];
      int row = id >> 4, c = (id & 15) * 4;
      *(ushort4*)&r0.p1.prj[row * 72 + c] =
          make_ushort4(f2bf(a.x * NORM), f2bf(a.y * NORM),
                       f2bf(a.z * NORM), f2bf(a.w * NORM));
    }
    const float* stg = wsb + 256 + fh * 128;
    for (int id = t; id < 2048; id += 512) {
      int row = id >> 5, c = (id & 31) * 4;
      float4 a = *(const float4*)(stg + (size_t)row * 256 + c);
      *(ushort4*)&sth[row * 136 + c] =
          make_ushort4(f2bf(a.x), f2bf(a.y), f2bf(a.z), f2bf(a.w));
    }
    __syncthreads();

    // feature GEMMs (transposed): M=feat(128), N=pos(128), K=d(64)
    // wave w = feat-block w; C: col=pos, row=feat -> pack 4 feats b64, pos-major
    #pragma unroll
    for (int px = 0; px < 2; ++px) {
      const ushort* xb = px ? r0.p1.xk : r0.p1.xq;
      ushort* xp = px ? kp : qp;
      floatx4 fa[8];
      #pragma unroll
      for (int nb = 0; nb < 8; ++nb) fa[nb] = (floatx4){0.f, 0.f, 0.f, 0.f};
      #pragma unroll
      for (int ks = 0; ks < 2; ++ks) {
        short8 a = *(const short8*)&r0.p1.prj[(w * 16 + lr) * 72 + ks * 32 + lg * 8];
        #pragma unroll
        for (int nb = 0; nb < 8; ++nb) {
          short8 b = *(const short8*)&xb[(nb * 16 + lr) * 72 + ks * 32 + lg * 8];
          fa[nb] = MFMA(a, b, fa[nb], 0, 0, 0);
        }
      }
      #pragma unroll
      for (int nb = 0; nb < 8; ++nb) {
        ushort4 u = make_ushort4(f2bf(sigm(fa[nb][0])), f2bf(sigm(fa[nb][1])),
                                 f2bf(sigm(fa[nb][2])), f2bf(sigm(fa[nb][3])));
        *(ushort4*)&xp[(nb * 16 + lr) * 136 + w * 16 + lg * 4] = u;
      }
    }
    __syncthreads();

    // A-GEMM: A += Qp Kp^T, M=q(128), N=k(128), K=f(128). wave w = q-block w.
    #pragma unroll
    for (int ks = 0; ks < 4; ++ks) {
      short8 aq = *(const short8*)&qp[(w * 16 + lr) * 136 + ks * 32 + lg * 8];
      #pragma unroll
      for (int nb = 0; nb < 8; ++nb) {
        if (nb <= w) {
          short8 bk = *(const short8*)&kp[(nb * 16 + lr) * 136 + ks * 32 + lg * 8];
          Aacc[nb] = MFMA(aq, bk, Aacc[nb], 0, 0, 0);
        }
      }
    }
    // O1^T: O^T += S_prev^T Qp^T, M=e(64), N=q(128), K=f(128)
    {
      const int eb = w & 3, qh = w >> 2;
      #pragma unroll
      for (int ks = 0; ks < 4; ++ks) {
        short8 as = *(const short8*)&sth[(eb * 16 + lr) * 136 + ks * 32 + lg * 8];
        #pragma unroll
        for (int nq = 0; nq < 4; ++nq) {
          short8 bq = *(const short8*)&qp[((qh * 4 + nq) * 16 + lr) * 136 + ks * 32 + lg * 8];
          Oacc[nq] = MFMA(as, bq, Oacc[nq], 0, 0, 0);
        }
      }
    }
    // dqr[i] += sum over this half's 128 feats: Qp[i][f]*(Kprev[f]+eps)
    // 4 threads/row, 32 feats each (4 x short8)
    {
      int row = t >> 2, seg = t & 3;
      float s = 0.f;
      #pragma unroll
      for (int i = 0; i < 4; ++i) {
        short8 vv = *(const short8*)&qp[row * 136 + seg * 32 + i * 8];
        #pragma unroll
        for (int j = 0; j < 8; ++j)
          s += bf2f((ushort)vv[j]) * (kprev[fh * 128 + seg * 32 + i * 8 + j] + EPS);
      }
      s += __shfl_xor(s, 1);
      s += __shfl_xor(s, 2);
      if ((t & 3) == 0) dqr[row] += s;
    }
    __syncthreads();
  }

  // causal mask + rowsum -> den
  #pragma unroll
  for (int r = 0; r < 4; ++r) {
    const int qrow = w * 16 + lg * 4 + r;
    float s = 0.f;
    #pragma unroll
    for (int nb = 0; nb < 8; ++nb) {
      float val = Aacc[nb][r];
      if (nb > w || nb * 16 + lr > qrow) val = 0.f;
      Aacc[nb][r] = val;
      s += val;
    }
    s += __shfl_xor(s, 1); s += __shfl_xor(s, 2);
    s += __shfl_xor(s, 4); s += __shfl_xor(s, 8);
    if (lr == 0) den[qrow] = s;
  }
  // scatter masked A -> ab (row-major bf16) ; stage V^T
  #pragma unroll
  for (int nb = 0; nb < 8; ++nb) {
    #pragma unroll
    for (int r = 0; r < 4; ++r) {
      r0.p2.ab[(w * 16 + lg * 4 + r) * 136 + nb * 16 + lr] = f2bf(Aacc[nb][r]);
    }
  }
  for (int id = t; id < 2048; id += 512) {
    float4 a = ((const float4*)vg)[id];
    int pos = id >> 4, e = (id & 15) * 4;
    r0.p2.vt[(e + 0) * 136 + pos] = f2bf(a.x);
    r0.p2.vt[(e + 1) * 136 + pos] = f2bf(a.y);
    r0.p2.vt[(e + 2) * 136 + pos] = f2bf(a.z);
    r0.p2.vt[(e + 3) * 136 + pos] = f2bf(a.w);
  }
  __syncthreads();

  // O2^T: O^T += V^T A^T, M=e(64), N=q(128), K=k(128); then divide and store
  {
    const int eb = w & 3, qh = w >> 2;
    #pragma unroll
    for (int ks = 0; ks < 4; ++ks) {
      short8 av = *(const short8*)&r0.p2.vt[(eb * 16 + lr) * 136 + ks * 32 + lg * 8];
      #pragma unroll
      for (int nq = 0; nq < 4; ++nq) {
        const int jb = qh * 4 + nq;
        if (ks <= (jb >> 1)) {
          short8 ba = *(const short8*)&r0.p2.ab[(jb * 16 + lr) * 136 + ks * 32 + lg * 8];
          Oacc[nq] = MFMA(av, ba, Oacc[nq], 0, 0, 0);
        }
      }
    }
    #pragma unroll
    for (int nq = 0; nq < 4; ++nq) {
      const int qrow = (qh * 4 + nq) * 16 + lr;
      float dinv = 1.f / (den[qrow] + dqr[qrow]);
      float4 o = make_float4(Oacc[nq][0] * dinv, Oacc[nq][1] * dinv,
                             Oacc[nq][2] * dinv, Oacc[nq][3] * dinv);
      *(float4*)(outg + (size_t)qrow * 64 + eb * 16 + lg * 4) = o;
    }
  }
}

extern "C" void kernel_launch(void* const* d_in, const int* in_sizes, int n_in,
                              void* d_out, int out_size, void* d_ws, size_t ws_size,
                              hipStream_t stream) {
  const float* q = (const float*)d_in[0];
  const float* k = (const float*)d_in[1];
  const float* v = (const float*)d_in[2];
  const float* proj = (const float*)d_in[3];
  float* out = (float*)d_out;
  float* sums = (float*)d_ws;  // 512*16640*4 = ~34 MB

  k1_chunksums<<<512, 512, 0, stream>>>(k, v, proj, sums);
  k2_scan<<<16 * 65, 256, 0, stream>>>(sums);
  k3_out<<<512, 512, 0, stream>>>(q, k, v, proj, sums, out);
}